// Round 4
// baseline (630.220 us; speedup 1.0000x reference)
//
#include <hip/hip_runtime.h>
#include <hip/hip_bf16.h>
#include <math.h>

#define N_TOK 32768
#define DIM   1024
#define HID   1024
#define NE    8

typedef __bf16 bf16_t;
typedef __bf16 bf16x8 __attribute__((ext_vector_type(8)));
typedef __bf16 bf16x4 __attribute__((ext_vector_type(4)));
typedef float  f32x4  __attribute__((ext_vector_type(4)));

#define GLOAD_LDS(g, s) __builtin_amdgcn_global_load_lds(                      \
    (const __attribute__((address_space(1))) void*)(g),                        \
    (__attribute__((address_space(3))) void*)(s), 16, 0, 0)

#define BARRIER() do { __builtin_amdgcn_s_barrier();                           \
                       asm volatile("" ::: "memory"); } while (0)

// ---------------------------------------------------------------------------
// expert_w f32 [E][D][H]  ->  bf16 [E][H][D]
// ---------------------------------------------------------------------------
__global__ __launch_bounds__(256) void convert_w_kernel(const float* __restrict__ W,
                                                        bf16_t* __restrict__ Wt) {
  __shared__ float tile[64][65];
  const int e  = blockIdx.z;
  const int d0 = blockIdx.x * 64;
  const int h0 = blockIdx.y * 64;
  const int t  = threadIdx.x;
  const float* src = W + (size_t)e * DIM * HID;
#pragma unroll
  for (int p = 0; p < 4; ++p) {
    int r = p * 16 + (t >> 4);
    int c = (t & 15) * 4;
    f32x4 v = *(const f32x4*)&src[(size_t)(d0 + r) * HID + h0 + c];
    tile[r][c + 0] = v[0]; tile[r][c + 1] = v[1];
    tile[r][c + 2] = v[2]; tile[r][c + 3] = v[3];
  }
  __syncthreads();
  const int hr = t >> 2, dseg = t & 3;
  bf16_t tmp[16];
#pragma unroll
  for (int j = 0; j < 16; ++j) tmp[j] = (bf16_t)tile[dseg * 16 + j][hr];
  bf16_t* dst = Wt + (size_t)e * HID * DIM + (size_t)(h0 + hr) * DIM + d0 + dseg * 16;
  *(bf16x8*)dst       = *(const bf16x8*)tmp;
  *(bf16x8*)(dst + 8) = *(const bf16x8*)(tmp + 8);
}

// ---------------------------------------------------------------------------
// Fused router (unchanged from round 3)
// ---------------------------------------------------------------------------
__global__ __launch_bounds__(256) void router_kernel(
    const float* __restrict__ x, const float* __restrict__ rw,
    const float* __restrict__ rb, bf16_t* __restrict__ xb,
    int* __restrict__ tok_list, float* __restrict__ w_list,
    int* __restrict__ gcnt) {
  __shared__ float rws[NE * DIM];
  __shared__ int   ce0[64], ce1[64];
  __shared__ float cw0[64], cw1[64];
  __shared__ int   lp0[64], lp1[64];
  __shared__ int   lcnt[2 * NE], gbase[2 * NE];
  const int t = threadIdx.x;
#pragma unroll
  for (int p = 0; p < 8; ++p) {
    int i4 = p * 256 + t;
    *(f32x4*)&rws[i4 * 4] = *(const f32x4*)&rw[i4 * 4];
  }
  if (t < 2 * NE) lcnt[t] = 0;
  __syncthreads();

  const int w = t >> 6, l = t & 63, ts = l >> 4, sub = l & 15;
  const int base = blockIdx.x * 64;
  for (int it = 0; it < 4; ++it) {
    const int lt    = it * 16 + w * 4 + ts;
    const int token = base + lt;
    const float* xrow  = x  + (size_t)token * DIM;
    bf16_t*      xbrow = xb + (size_t)token * DIM;
    double acc[NE];
#pragma unroll
    for (int e = 0; e < NE; ++e) acc[e] = 0.0;
    for (int p = 0; p < 16; ++p) {
      const int d = p * 64 + sub * 4;
      f32x4 xv = *(const f32x4*)&xrow[d];
      bf16x4 bv;
#pragma unroll
      for (int j = 0; j < 4; ++j) bv[j] = (bf16_t)xv[j];
      *(bf16x4*)&xbrow[d] = bv;
#pragma unroll
      for (int e = 0; e < NE; ++e) {
        f32x4 rv = *(const f32x4*)&rws[e * DIM + d];
        acc[e] += (double)xv[0] * (double)rv[0] + (double)xv[1] * (double)rv[1]
                + (double)xv[2] * (double)rv[2] + (double)xv[3] * (double)rv[3];
      }
    }
#pragma unroll
    for (int e = 0; e < NE; ++e) {
      double v = acc[e];
      v += __shfl_xor(v, 1, 16);
      v += __shfl_xor(v, 2, 16);
      v += __shfl_xor(v, 4, 16);
      v += __shfl_xor(v, 8, 16);
      acc[e] = v;
    }
    if (sub == 0) {
      double lv[NE];
#pragma unroll
      for (int e = 0; e < NE; ++e) lv[e] = acc[e] + (double)rb[e];
      int e0 = 0; double v0 = lv[0];
#pragma unroll
      for (int e = 1; e < NE; ++e) if (lv[e] > v0) { v0 = lv[e]; e0 = e; }
      int e1 = -1; double v1 = -1.0e300;
#pragma unroll
      for (int e = 0; e < NE; ++e) if (e != e0 && lv[e] > v1) { v1 = lv[e]; e1 = e; }
      const float ef = expf((float)(v1 - v0));
      const float s  = 1.0f + ef;
      ce0[lt] = e0; ce1[lt] = e1;
      cw0[lt] = 1.0f / s; cw1[lt] = ef / s;
    }
  }
  __syncthreads();
  if (t < 64) {
    lp0[t] = atomicAdd(&lcnt[ce0[t] * 2 + 0], 1);
    lp1[t] = atomicAdd(&lcnt[ce1[t] * 2 + 1], 1);
  }
  __syncthreads();
  if (t < 2 * NE) gbase[t] = atomicAdd(&gcnt[t], lcnt[t]);
  __syncthreads();
  if (t < 64) {
    const int token = base + t;
    const int le0 = ce0[t] * 2 + 0, le1 = ce1[t] * 2 + 1;
    const int p0 = gbase[le0] + lp0[t];
    const int p1 = gbase[le1] + lp1[t];
    tok_list[le0 * N_TOK + p0] = token;  w_list[le0 * N_TOK + p0] = cw0[t];
    tok_list[le1 * N_TOK + p1] = token;  w_list[le1 * N_TOK + p1] = cw1[t];
  }
}

// ---------------------------------------------------------------------------
// Grouped GEMM, 256x256 tile, BK=64 (two K=32 halves), 8 waves (2Mx4N),
// 8-phase schedule with counted vmcnt (T3+T4), LDS swizzle (T2), setprio (T5).
// LDS (dynamic, 128KB, bf16 elems):
//   A(buf,kk) = buf*16384 + kk*8192       (each half: [256 rows][32 k])
//   B(buf,kk) = 32768 + buf*16384 + kk*8192
// Swizzle: LDS (row, slot16B) holds global k-seg  slot ^ ((row>>1)&3).
// Half-tile stream s: tile=s>>2, type s&3 = {A-k0, B-k0, A-k1, B-k1}.
// Steady state: 3 half-tiles (6 loads) in flight -> vmcnt(6) per boundary.
// ---------------------------------------------------------------------------
#define BM 256
#define BN 256
#define BK 64
#define NT (DIM / BK)     // 16 K-tiles, 64 half-tiles
#define GX 32             // 32*256 = 8192 row capacity per (expert,slot)

#define MF(x, y, m, n) acc[m][n] = \
    __builtin_amdgcn_mfma_f32_16x16x32_bf16((x), (y), acc[m][n], 0, 0, 0)

#define MFMA16(MB) do {                                                        \
    __builtin_amdgcn_s_setprio(1);                                             \
    MF(a0, b0, (MB)+0, 0); MF(a0, b1, (MB)+0, 1);                              \
    MF(a0, b2, (MB)+0, 2); MF(a0, b3, (MB)+0, 3);                              \
    MF(a1, b0, (MB)+1, 0); MF(a1, b1, (MB)+1, 1);                              \
    MF(a1, b2, (MB)+1, 2); MF(a1, b3, (MB)+1, 3);                              \
    MF(a2, b0, (MB)+2, 0); MF(a2, b1, (MB)+2, 1);                              \
    MF(a2, b2, (MB)+2, 2); MF(a2, b3, (MB)+2, 3);                              \
    MF(a3, b0, (MB)+3, 0); MF(a3, b1, (MB)+3, 1);                              \
    MF(a3, b2, (MB)+3, 2); MF(a3, b3, (MB)+3, 3);                              \
    __builtin_amdgcn_s_setprio(0);                                             \
  } while (0)

__global__ __launch_bounds__(512, 2) void moe_gemm_kernel(
    const bf16_t* __restrict__ xb, const bf16_t* __restrict__ wt,
    const float* __restrict__ eb, const int* __restrict__ tok_list,
    const float* __restrict__ w_list, const int* __restrict__ gcnt,
    float* __restrict__ out, int slot) {
  // XCD swizzle (1024 wgs, 128/XCD = one expert); by fastest for L2 reuse.
  const int f  = blockIdx.x;
  const int wg = (f & 7) * (GX * (HID / BN) * NE / 8) + (f >> 3);
  const int e  = wg / (GX * (HID / BN));
  const int rr = wg % (GX * (HID / BN));
  const int bx = rr >> 2;
  const int by = rr & 3;

  const int le = e * 2 + slot;
  const int c  = gcnt[le];
  const int m0 = bx * BM;
  if (m0 >= c) return;
  const int h0 = by * BN;

  extern __shared__ bf16_t lds[];
  __shared__ int   tok_s[BM];
  __shared__ float w_s[BM];

  const int t = threadIdx.x;
  if (t < BM) {
    int r  = m0 + t;
    int rc = r < c ? r : c - 1;
    tok_s[t] = tok_list[le * N_TOK + rc];
    w_s[t]   = (r < c) ? w_list[le * N_TOK + r] : 0.0f;
  }
  __syncthreads();

  // ---- staging: unit u in [0,1024): row=u>>2, slot16B=u&3; thread t owns
  //      u=t and u=t+512; LDS dest linear (elem u*8), source carries swizzle.
  const int srow = t >> 2, sslot = t & 3;
  const int sswz = (sslot ^ ((srow >> 1) & 3)) * 8;
  const bf16_t* wbase = wt + (size_t)e * HID * DIM;
  const bf16_t* aR0 = xb + (size_t)tok_s[srow] * DIM + sswz;
  const bf16_t* aR1 = xb + (size_t)tok_s[srow + 128] * DIM + sswz;
  const bf16_t* bR0 = wbase + (size_t)(h0 + srow) * DIM + sswz;
  const bf16_t* bR1 = wbase + (size_t)(h0 + srow + 128) * DIM + sswz;

  auto stage_half = [&](int s_) {
    if (s_ < 4 * NT) {
      const int tile_ = s_ >> 2;
      const int typ_  = s_ & 3;
      const int buf_  = tile_ & 1;
      const int kk_   = typ_ >> 1;
      const int koff_ = tile_ * BK + kk_ * 32;
      bf16_t* db_ = lds + ((typ_ & 1) ? 32768 : 0) + buf_ * 16384 + kk_ * 8192
                        + t * 8;
      if (typ_ & 1) { GLOAD_LDS(bR0 + koff_, db_); GLOAD_LDS(bR1 + koff_, db_ + 4096); }
      else          { GLOAD_LDS(aR0 + koff_, db_); GLOAD_LDS(aR1 + koff_, db_ + 4096); }
    }
  };

  // ---- MFMA geometry ----
  const int w  = t >> 6, l = t & 63;
  const int wr = w >> 2, wc = w & 3;           // 2M x 4N waves
  const int fr = l & 15, fq = l >> 4;
  const int rswz = (fq ^ ((fr >> 1) & 3)) * 8; // read-side swizzle
  const int aoff = (wr * 128 + fr) * 32 + rswz;
  const int boff = (wc * 64 + fr) * 32 + rswz;

  f32x4 acc[8][4];
  const f32x4 fzero = {0.0f, 0.0f, 0.0f, 0.0f};
#pragma unroll
  for (int m = 0; m < 8; ++m)
#pragma unroll
    for (int n = 0; n < 4; ++n) acc[m][n] = fzero;

  // ---- prologue: issue halves 0..6; land tile 0 (4 halves), 3 in flight ----
  stage_half(0); stage_half(1); stage_half(2); stage_half(3);
  stage_half(4); stage_half(5); stage_half(6);
  asm volatile("s_waitcnt vmcnt(6)" ::: "memory");
  BARRIER();
  int s = 7;

#pragma unroll 2
  for (int kt = 0; kt < NT; ++kt) {
    const int buf = kt & 1;
    const bf16_t* Ab0 = lds + buf * 16384;
    const bf16_t* Ab1 = Ab0 + 8192;
    const bf16_t* Bb0 = lds + 32768 + buf * 16384;
    const bf16_t* Bb1 = Bb0 + 8192;
    bf16x8 a0, a1, a2, a3, b0, b1, b2, b3;

    // phase 1: m-frags 0..3, kk=0
    a0 = *(const bf16x8*)(Ab0 + aoff + 0 * 512);
    a1 = *(const bf16x8*)(Ab0 + aoff + 1 * 512);
    a2 = *(const bf16x8*)(Ab0 + aoff + 2 * 512);
    a3 = *(const bf16x8*)(Ab0 + aoff + 3 * 512);
    b0 = *(const bf16x8*)(Bb0 + boff + 0 * 512);
    b1 = *(const bf16x8*)(Bb0 + boff + 1 * 512);
    b2 = *(const bf16x8*)(Bb0 + boff + 2 * 512);
    b3 = *(const bf16x8*)(Bb0 + boff + 3 * 512);
    stage_half(s + 0);
    BARRIER();
    MFMA16(0);
    BARRIER();

    // phase 2: m-frags 4..7, kk=0 (reuse b0..b3)
    a0 = *(const bf16x8*)(Ab0 + aoff + 4 * 512);
    a1 = *(const bf16x8*)(Ab0 + aoff + 5 * 512);
    a2 = *(const bf16x8*)(Ab0 + aoff + 6 * 512);
    a3 = *(const bf16x8*)(Ab0 + aoff + 7 * 512);
    stage_half(s + 1);
    BARRIER();
    MFMA16(4);
    BARRIER();

    // phase 3: m-frags 0..3, kk=1
    a0 = *(const bf16x8*)(Ab1 + aoff + 0 * 512);
    a1 = *(const bf16x8*)(Ab1 + aoff + 1 * 512);
    a2 = *(const bf16x8*)(Ab1 + aoff + 2 * 512);
    a3 = *(const bf16x8*)(Ab1 + aoff + 3 * 512);
    b0 = *(const bf16x8*)(Bb1 + boff + 0 * 512);
    b1 = *(const bf16x8*)(Bb1 + boff + 1 * 512);
    b2 = *(const bf16x8*)(Bb1 + boff + 2 * 512);
    b3 = *(const bf16x8*)(Bb1 + boff + 3 * 512);
    stage_half(s + 2);
    BARRIER();
    MFMA16(0);
    BARRIER();

    // phase 4: m-frags 4..7, kk=1  + tile boundary (counted vmcnt)
    a0 = *(const bf16x8*)(Ab1 + aoff + 4 * 512);
    a1 = *(const bf16x8*)(Ab1 + aoff + 5 * 512);
    a2 = *(const bf16x8*)(Ab1 + aoff + 6 * 512);
    a3 = *(const bf16x8*)(Ab1 + aoff + 7 * 512);
    stage_half(s + 3);
    BARRIER();
    MFMA16(4);
    if (kt < NT - 2)       asm volatile("s_waitcnt vmcnt(6)" ::: "memory");
    else if (kt == NT - 2) asm volatile("s_waitcnt vmcnt(0)" ::: "memory");
    BARRIER();
    s += 4;
  }

  // ---- epilogue: slot 0 stores, slot 1 read-modify-write (unique owner) ----
#pragma unroll
  for (int nf = 0; nf < 4; ++nf) {
    const int h = h0 + wc * 64 + nf * 16 + fr;
    const float bias = eb[e * HID + h];
#pragma unroll
    for (int mf = 0; mf < 8; ++mf) {
#pragma unroll
      for (int q = 0; q < 4; ++q) {
        const int r = wr * 128 + mf * 16 + fq * 4 + q;
        const float wv = w_s[r];
        if (wv != 0.0f) {
          const size_t o = (size_t)tok_s[r] * HID + h;
          const float v = wv * (acc[mf][nf][q] + bias);
          if (slot == 0) out[o] = v;
          else           out[o] = out[o] + v;
        }
      }
    }
  }
}

// ---------------------------------------------------------------------------
extern "C" void kernel_launch(void* const* d_in, const int* in_sizes, int n_in,
                              void* d_out, int out_size, void* d_ws, size_t ws_size,
                              hipStream_t stream) {
  const float* x  = (const float*)d_in[0];
  const float* rw = (const float*)d_in[1];
  const float* rb = (const float*)d_in[2];
  const float* ew = (const float*)d_in[3];
  const float* eb = (const float*)d_in[4];
  float* out = (float*)d_out;

  char* ws = (char*)d_ws;
  bf16_t* xb       = (bf16_t*)(ws);                        // 64 MB
  bf16_t* wt       = (bf16_t*)(ws + 67108864);             // 16 MB
  int*    tok_list = (int*)   (ws + 83886080);             // 2 MB (16 lists)
  float*  w_list   = (float*) (ws + 85983232);             // 2 MB
  int*    gcnt     = (int*)   (ws + 88080384);             // 64 B

  hipMemsetAsync(gcnt, 0, 2 * NE * sizeof(int), stream);

  convert_w_kernel<<<dim3(DIM / 64, HID / 64, NE), 256, 0, stream>>>(ew, wt);
  router_kernel<<<dim3(N_TOK / 64), 256, 0, stream>>>(x, rw, rb, xb,
                                                      tok_list, w_list, gcnt);

  hipFuncSetAttribute((const void*)moe_gemm_kernel,
                      hipFuncAttributeMaxDynamicSharedMemorySize, 131072);
  const int nwg = GX * (HID / BN) * NE;   // 1024
  moe_gemm_kernel<<<nwg, 512, 131072, stream>>>(xb, wt, eb, tok_list, w_list,
                                                gcnt, out, 0);
  moe_gemm_kernel<<<nwg, 512, 131072, stream>>>(xb, wt, eb, tok_list, w_list,
                                                gcnt, out, 1);
}